// Round 11
// baseline (156.511 us; speedup 1.0000x reference)
//
#include <hip/hip_runtime.h>

#define IN_CH   128
#define HIDDEN  256
#define N_GRAPHS 64
#define GN 64  // nodes per gemm block

typedef short short8 __attribute__((ext_vector_type(8)));
typedef float f32x4 __attribute__((ext_vector_type(4)));

__device__ inline unsigned f2bf(float f) {
  unsigned u = __float_as_uint(f);
  return (u + 0x7fffu + ((u >> 16) & 1u)) >> 16;
}
__device__ inline unsigned pack2(float lo, float hi) {
  return (f2bf(hi) << 16) | f2bf(lo);
}
__device__ inline void acc8(uint4 v, float w, float* A) {
  A[0] += w * __uint_as_float(v.x << 16);
  A[1] += w * __uint_as_float(v.x & 0xffff0000u);
  A[2] += w * __uint_as_float(v.y << 16);
  A[3] += w * __uint_as_float(v.y & 0xffff0000u);
  A[4] += w * __uint_as_float(v.z << 16);
  A[5] += w * __uint_as_float(v.z & 0xffff0000u);
  A[6] += w * __uint_as_float(v.w << 16);
  A[7] += w * __uint_as_float(v.w & 0xffff0000u);
}

// Fused preprocessing with 4-way MLP: x->bf16 cast (grid-stride), w1->bf16
// transpose, deg count + edge rank (4 independent atomics in flight/thread).
__global__ __launch_bounds__(256) void k_pre(
    const float* __restrict__ x, ushort* __restrict__ xh,
    const float* __restrict__ w1, ushort* __restrict__ w1t,
    const int* __restrict__ dst, int* __restrict__ deg,
    int* __restrict__ rank, int total8, int e, int nthreads) {
  int i0 = blockIdx.x * blockDim.x + threadIdx.x;
  // ---- x cast: grid-stride, 16B in / 16B out per iter
  for (int i = i0; i < total8; i += nthreads) {
    const float4* xp = reinterpret_cast<const float4*>(x) + (size_t)i * 2;
    float4 a = xp[0], b = xp[1];
    uint4 o;
    o.x = pack2(a.x, a.y);
    o.y = pack2(a.z, a.w);
    o.z = pack2(b.x, b.y);
    o.w = pack2(b.z, b.w);
    reinterpret_cast<uint4*>(xh)[i] = o;
  }
  // ---- w1 transpose+cast
  if (i0 < HIDDEN * IN_CH) {
    int nn = i0 >> 7, k = i0 & 127;
    w1t[i0] = (ushort)f2bf(w1[k * 256 + nn]);
  }
  // ---- deg/rank: 4 edges per thread, strided (coalesced), atomics pipelined
  {
    int j0 = i0, j1 = i0 + nthreads, j2 = i0 + 2 * nthreads, j3 = i0 + 3 * nthreads;
    int d0 = (j0 < e) ? dst[j0] : 0;
    int d1 = (j1 < e) ? dst[j1] : 0;
    int d2 = (j2 < e) ? dst[j2] : 0;
    int d3 = (j3 < e) ? dst[j3] : 0;
    int r0 = 0, r1 = 0, r2 = 0, r3 = 0;
    if (j0 < e) r0 = atomicAdd(&deg[d0], 1);
    if (j1 < e) r1 = atomicAdd(&deg[d1], 1);
    if (j2 < e) r2 = atomicAdd(&deg[d2], 1);
    if (j3 < e) r3 = atomicAdd(&deg[d3], 1);
    if (j0 < e) rank[j0] = r0;
    if (j1 < e) rank[j1] = r1;
    if (j2 < e) rank[j2] = r2;
    if (j3 < e) rank[j3] = r3;
  }
}

__global__ __launch_bounds__(1024) void k_scan1(const int* __restrict__ deg,
    int* __restrict__ offs, int* __restrict__ bsum, int n) {
  __shared__ int sm[1024];
  int t = threadIdx.x;
  int i = blockIdx.x * 1024 + t;
  int v = (i < n) ? deg[i] : 0;
  sm[t] = v;
  __syncthreads();
  for (int d = 1; d < 1024; d <<= 1) {
    int add = (t >= d) ? sm[t - d] : 0;
    __syncthreads();
    sm[t] += add;
    __syncthreads();
  }
  if (i < n) offs[i] = sm[t] - v;  // exclusive
  if (t == 1023) bsum[blockIdx.x] = sm[1023];
}

// Fused scan2+scan3: wave 0 redundantly shfl-scans block sums (nb<=64),
// then all threads apply block offset + compute dinv.
__global__ void k_scan23(int* __restrict__ offs, const int* __restrict__ bsum,
                         const int* __restrict__ deg, float* __restrict__ dinv,
                         int n, int nb) {
  __shared__ int bofs_s[64];
  int t = threadIdx.x;
  if (t < 64) {
    int orig = (t < nb) ? bsum[t] : 0;
    int v = orig;
    for (int d = 1; d < 64; d <<= 1) {
      int u = __shfl_up(v, d, 64);
      if (t >= d) v += u;
    }
    bofs_s[t] = v - orig;  // exclusive
  }
  __syncthreads();
  int i = blockIdx.x * blockDim.x + t;
  if (i < n) {
    offs[i] += bofs_s[i >> 10];
    dinv[i] = 1.0f / sqrtf((float)(deg[i] + 1));
  }
}

// atomic-free CSR fill using precomputed ranks
__global__ void k_place(const int* __restrict__ src, const int* __restrict__ dst,
                        const int* __restrict__ rank, const int* __restrict__ offs,
                        int* __restrict__ csr, int e) {
  int i = blockIdx.x * blockDim.x + threadIdx.x;
  if (i < e) csr[offs[dst[i]] + rank[i]] = src[i];
}

// 4 nodes/block. lane = es*16+cg; es = edge slot (4), cg = channel group
// (16 x 8 bf16 = 16B). 4-deep predicated slots -> 16 gather rows in flight.
__global__ __launch_bounds__(256) void k_agg(const ushort* __restrict__ xh,
    const int* __restrict__ csr, const int* __restrict__ offs,
    const int* __restrict__ degc, const float* __restrict__ dinv,
    ushort* __restrict__ yh, int n) {
  int node = blockIdx.x * 4 + (threadIdx.x >> 6);
  if (node >= n) return;
  int lane = threadIdx.x & 63;
  int es = lane >> 4;
  int cg = lane & 15;
  int o = offs[node], c = degc[node];
  float A[8] = {0.f, 0.f, 0.f, 0.f, 0.f, 0.f, 0.f, 0.f};
  for (int it = 0; it < c; it += 16) {
    float w[4];
    uint4 v[4];
#pragma unroll
    for (int u = 0; u < 4; ++u) {
      int ii = it + u * 4 + es;
      bool val = ii < c;
      int s = val ? csr[o + ii] : node;   // junk slot -> own row (cache hit)
      w[u] = val ? dinv[s] : 0.f;
      v[u] = *reinterpret_cast<const uint4*>(&xh[(size_t)s * IN_CH + cg * 8]);
    }
#pragma unroll
    for (int u = 0; u < 4; ++u) acc8(v[u], w[u], A);
  }
#pragma unroll
  for (int k = 0; k < 8; ++k) {
    A[k] += __shfl_xor(A[k], 16, 64);
    A[k] += __shfl_xor(A[k], 32, 64);
  }
  if (es == 0) {
    float dn = dinv[node];
    uint4 xs = *reinterpret_cast<const uint4*>(&xh[(size_t)node * IN_CH + cg * 8]);
    float xv[8] = {0.f, 0.f, 0.f, 0.f, 0.f, 0.f, 0.f, 0.f};
    acc8(xs, dn, xv);  // xv = x_self * dn
    float v[8];
#pragma unroll
    for (int k = 0; k < 8; ++k) v[k] = (A[k] + xv[k]) * dn;
    uint4 w;
    w.x = pack2(v[0], v[1]);
    w.y = pack2(v[2], v[3]);
    w.z = pack2(v[4], v[5]);
    w.w = pack2(v[6], v[7]);
    *reinterpret_cast<uint4*>(&yh[(size_t)node * IN_CH + cg * 8]) = w;
  }
}

// MFMA GEMM(128->256 bf16)+bias+relu fused with per-graph pooling.
// 256 threads = 4 waves; wave w owns hidden cols [w*64, w*64+64).
// Per wave: 4x4 tiles of 16x16, K = 4 chunks of 32. No operand LDS.
__global__ __launch_bounds__(256) void k_gemmpool(
    const ushort* __restrict__ yh, const ushort* __restrict__ w1t,
    const float* __restrict__ b1, const int* __restrict__ batch,
    float* __restrict__ pooled, int n) {
  __shared__ float part[4][HIDDEN];  // 4 KB
  __shared__ int bl[GN];
  int t = threadIdx.x;
  int node0 = blockIdx.x * GN;

  if (t < GN) {
    int nd = node0 + t;
    bl[t] = (nd < n) ? batch[nd] : -1;
  }
  {
    float* pp = &part[0][0];
    for (int i = t; i < 4 * HIDDEN; i += 256) pp[i] = 0.f;
  }

  int wv = t >> 6, l = t & 63;
  int lr = l & 15;   // A-row / B-col / D-col index within tile
  int lk = l >> 4;   // k-slot (A/B), row-group (D)
  int colbase = wv * 64;

  f32x4 acc[4][4];
#pragma unroll
  for (int m = 0; m < 4; ++m)
#pragma unroll
    for (int nn = 0; nn < 4; ++nn) acc[m][nn] = (f32x4){0.f, 0.f, 0.f, 0.f};

#pragma unroll
  for (int kc = 0; kc < 4; ++kc) {
    short8 a[4], b[4];
#pragma unroll
    for (int m = 0; m < 4; ++m)
      a[m] = *reinterpret_cast<const short8*>(
          &yh[(size_t)(node0 + m * 16 + lr) * IN_CH + kc * 32 + lk * 8]);
#pragma unroll
    for (int nn = 0; nn < 4; ++nn)
      b[nn] = *reinterpret_cast<const short8*>(
          &w1t[(size_t)(colbase + nn * 16 + lr) * IN_CH + kc * 32 + lk * 8]);
#pragma unroll
    for (int m = 0; m < 4; ++m)
#pragma unroll
      for (int nn = 0; nn < 4; ++nn)
        acc[m][nn] = __builtin_amdgcn_mfma_f32_16x16x32_bf16(a[m], b[nn], acc[m][nn], 0, 0, 0);
  }

  __syncthreads();  // bl + part ready; mfma results in regs

  float bias[4];
#pragma unroll
  for (int nn = 0; nn < 4; ++nn) bias[nn] = b1[colbase + nn * 16 + lr];
  int g0 = bl[0];

#pragma unroll
  for (int m = 0; m < 4; ++m) {
    float s[4] = {0.f, 0.f, 0.f, 0.f};
    int gcur = -1;
#pragma unroll
    for (int j = 0; j < 4; ++j) {
      int row = m * 16 + lk * 4 + j;
      int node = node0 + row;
      int g = (node < n) ? bl[row] : -1;
      if (g != gcur) {
        if (gcur >= 0) {
          int gi = gcur - g0;
          if (gi < 4) {
#pragma unroll
            for (int nn = 0; nn < 4; ++nn)
              atomicAdd(&part[gi][colbase + nn * 16 + lr], s[nn]);
          } else {
#pragma unroll
            for (int nn = 0; nn < 4; ++nn)
              atomicAdd(&pooled[gcur * HIDDEN + colbase + nn * 16 + lr], s[nn]);
          }
        }
#pragma unroll
        for (int u = 0; u < 4; ++u) s[u] = 0.f;
        gcur = g;
      }
      if (g >= 0) {
#pragma unroll
        for (int nn = 0; nn < 4; ++nn)
          s[nn] += fmaxf(acc[m][nn][j] + bias[nn], 0.f);
      }
    }
    if (gcur >= 0) {
      int gi = gcur - g0;
      if (gi < 4) {
#pragma unroll
        for (int nn = 0; nn < 4; ++nn)
          atomicAdd(&part[gi][colbase + nn * 16 + lr], s[nn]);
      } else {
#pragma unroll
        for (int nn = 0; nn < 4; ++nn)
          atomicAdd(&pooled[gcur * HIDDEN + colbase + nn * 16 + lr], s[nn]);
      }
    }
  }

  __syncthreads();
  int lastIdx = min(GN, n - node0) - 1;
  int gmax = bl[lastIdx];
  int span = gmax - g0;
  if (span > 3) span = 3;
  for (int gi = 0; gi <= span; ++gi) {
    atomicAdd(&pooled[(g0 + gi) * HIDDEN + t], part[gi][t]);
  }
}

// One block per graph: cnt via binary search (batch sorted), mean,
// z = relu(p@w2+b2), out = z@w3+b3  (all fp32)
__global__ __launch_bounds__(256) void k_head(const float* __restrict__ pooled,
    const int* __restrict__ batch, int n, const float* __restrict__ w2,
    const float* __restrict__ b2, const float* __restrict__ w3,
    const float* __restrict__ b3, float* __restrict__ out) {
  __shared__ float p[256];
  __shared__ float red[4];
  __shared__ int scnt;
  int g = blockIdx.x, t = threadIdx.x;
  if (t == 0) {
    int lo = 0, hi = n;
    while (lo < hi) { int mid = (lo + hi) >> 1; if (batch[mid] < g) lo = mid + 1; else hi = mid; }
    int a = lo;
    lo = 0; hi = n;
    int g1 = g + 1;
    while (lo < hi) { int mid = (lo + hi) >> 1; if (batch[mid] < g1) lo = mid + 1; else hi = mid; }
    scnt = lo - a;
  }
  __syncthreads();
  float c = (float)max(scnt, 1);
  p[t] = pooled[g * HIDDEN + t] / c;
  __syncthreads();
  float a = 0.f;
  for (int k = 0; k < 256; ++k) a += p[k] * w2[k * 256 + t];
  a += b2[t];
  a = fmaxf(a, 0.f);
  float part = a * w3[t];
  for (int off = 32; off > 0; off >>= 1) part += __shfl_down(part, off, 64);
  if ((t & 63) == 0) red[t >> 6] = part;
  __syncthreads();
  if (t == 0) out[g] = red[0] + red[1] + red[2] + red[3] + b3[0];
}

extern "C" void kernel_launch(void* const* d_in, const int* in_sizes, int n_in,
                              void* d_out, int out_size, void* d_ws, size_t ws_size,
                              hipStream_t stream) {
  const float* x    = (const float*)d_in[0];
  const int*   ei   = (const int*)d_in[1];
  const int*   batch= (const int*)d_in[2];
  const float* w1   = (const float*)d_in[3];
  const float* b1   = (const float*)d_in[4];
  const float* w2   = (const float*)d_in[5];
  const float* b2   = (const float*)d_in[6];
  const float* w3   = (const float*)d_in[7];
  const float* b3   = (const float*)d_in[8];
  float* out = (float*)d_out;

  int N = in_sizes[2];
  int E = in_sizes[1] / 2;
  const int* esrc = ei;
  const int* edst = ei + E;

  // layout (ints): [deg_i N][pooled 16384] (one zero-fill) [offs N][dinv N]
  // [bsum 64][rank E][csr E][w1t 16384][xh N*64][yh NP*64]
  int* W = (int*)d_ws;
  int*    deg_i  = W;
  float*  pooled = (float*)(W + N);
  int*    offs   = W + N + N_GRAPHS * HIDDEN;
  float*  dinv   = (float*)(offs + N);
  int*    bsum   = (int*)(dinv + N);
  int*    rank   = bsum + 64;
  int*    csr    = rank + E;
  ushort* w1t    = (ushort*)(csr + E);
  ushort* xh     = (ushort*)(csr + E + 16384);
  ushort* yh     = xh + (size_t)N * IN_CH;

  hipMemsetAsync(deg_i, 0, (size_t)(N + N_GRAPHS * HIDDEN) * sizeof(int), stream);

  const int tb = 256;
  int total8 = N * 16;
  // threads = enough for E/4 edges each doing 4, and grid-stride cast
  int nthreads = ((max((E + 3) / 4, HIDDEN * IN_CH) + tb - 1) / tb) * tb;
  k_pre<<<nthreads / tb, tb, 0, stream>>>(x, xh, w1, w1t, edst, deg_i, rank,
                                          total8, E, nthreads);
  int nb = (N + 1023) / 1024;
  k_scan1<<<nb, 1024, 0, stream>>>(deg_i, offs, bsum, N);
  k_scan23<<<(N + tb - 1) / tb, tb, 0, stream>>>(offs, bsum, deg_i, dinv, N, nb);
  k_place<<<(E + tb - 1) / tb, tb, 0, stream>>>(esrc, edst, rank, offs, csr, E);
  k_agg<<<(N + 3) / 4, 256, 0, stream>>>(xh, csr, offs, deg_i, dinv, yh, N);
  k_gemmpool<<<(N + GN - 1) / GN, 256, 0, stream>>>(yh, w1t, b1, batch, pooled, N);
  k_head<<<N_GRAPHS, 256, 0, stream>>>(pooled, batch, N, w2, b2, w3, b3, out);
}

// Round 13
// 130.848 us; speedup vs baseline: 1.1961x; 1.1961x over previous
//
#include <hip/hip_runtime.h>

#define IN_CH   128
#define HIDDEN  256
#define N_GRAPHS 64
#define GN 64     // nodes per gemm block
#define NPB 128   // nodes per bucket
#define MAXBUCK 512
#define NBLK 400  // edge-processing blocks

typedef short short8 __attribute__((ext_vector_type(8)));
typedef float f32x4 __attribute__((ext_vector_type(4)));

__device__ inline unsigned f2bf(float f) {
  unsigned u = __float_as_uint(f);
  return (u + 0x7fffu + ((u >> 16) & 1u)) >> 16;
}
__device__ inline unsigned pack2(float lo, float hi) {
  return (f2bf(hi) << 16) | f2bf(lo);
}
__device__ inline void acc8(uint4 v, float w, float* A) {
  A[0] += w * __uint_as_float(v.x << 16);
  A[1] += w * __uint_as_float(v.x & 0xffff0000u);
  A[2] += w * __uint_as_float(v.y << 16);
  A[3] += w * __uint_as_float(v.y & 0xffff0000u);
  A[4] += w * __uint_as_float(v.z << 16);
  A[5] += w * __uint_as_float(v.z & 0xffff0000u);
  A[6] += w * __uint_as_float(v.w << 16);
  A[7] += w * __uint_as_float(v.w & 0xffff0000u);
}

// P1: x->bf16 + w1->bf16^T casts (grid-stride) + per-block LDS bucket histogram.
__global__ __launch_bounds__(256) void k_p1(
    const float* __restrict__ x, ushort* __restrict__ xh,
    const float* __restrict__ w1, ushort* __restrict__ w1t,
    const int* __restrict__ dst, int* __restrict__ ghist,
    int total8, int e, int nbuck, int chunk) {
  __shared__ int h[MAXBUCK];
  int t = threadIdx.x, b = blockIdx.x;
  for (int k = t; k < nbuck; k += 256) h[k] = 0;
  int gid = b * 256 + t;
  const int nthr = NBLK * 256;
  for (int i = gid; i < total8; i += nthr) {
    const float4* xp = reinterpret_cast<const float4*>(x) + (size_t)i * 2;
    float4 a = xp[0], bb = xp[1];
    uint4 o;
    o.x = pack2(a.x, a.y);
    o.y = pack2(a.z, a.w);
    o.z = pack2(bb.x, bb.y);
    o.w = pack2(bb.z, bb.w);
    reinterpret_cast<uint4*>(xh)[i] = o;
  }
  if (gid < HIDDEN * IN_CH) {
    int nn = gid >> 7, k = gid & 127;
    w1t[gid] = (ushort)f2bf(w1[k * 256 + nn]);
  }
  __syncthreads();
  int s = b * chunk, eend = min(e, s + chunk);
  for (int i = s + t; i < eend; i += 256) atomicAdd(&h[dst[i] >> 7], 1);
  __syncthreads();
  for (int k = t; k < nbuck; k += 256) ghist[b * MAXBUCK + k] = h[k];
}

// P2a: per-bucket exclusive scan over the NBLK blocks; emit bucket totals.
__global__ __launch_bounds__(512) void k_p2a(const int* __restrict__ ghist,
    int* __restrict__ boff, int* __restrict__ total, int nbuck) {
  __shared__ int sm[512];
  int k = blockIdx.x, t = threadIdx.x;
  int v = (t < NBLK) ? ghist[t * MAXBUCK + k] : 0;
  sm[t] = v;
  __syncthreads();
  for (int d = 1; d < 512; d <<= 1) {
    int add = (t >= d) ? sm[t - d] : 0;
    __syncthreads();
    sm[t] += add;
    __syncthreads();
  }
  if (t < NBLK) boff[k * NBLK + t] = sm[t] - v;
  if (t == 511) total[k] = sm[511];
}

// P2b: exclusive scan of bucket totals -> tbase.
__global__ __launch_bounds__(512) void k_p2b(const int* __restrict__ total,
    int* __restrict__ tbase, int nbuck) {
  __shared__ int sm[512];
  int t = threadIdx.x;
  int v = (t < nbuck) ? total[t] : 0;
  sm[t] = v;
  __syncthreads();
  for (int d = 1; d < 512; d <<= 1) {
    int add = (t >= d) ? sm[t - d] : 0;
    __syncthreads();
    sm[t] += add;
    __syncthreads();
  }
  if (t < nbuck) tbase[t] = sm[t] - v;
}

// P3: scatter edges into bucket-contiguous ebuf via LDS cursors.
__global__ __launch_bounds__(256) void k_p3(
    const int* __restrict__ src, const int* __restrict__ dst,
    const int* __restrict__ boff, const int* __restrict__ tbase,
    int2* __restrict__ ebuf, int e, int nbuck, int chunk) {
  __shared__ int cur[MAXBUCK];
  int t = threadIdx.x, b = blockIdx.x;
  for (int k = t; k < nbuck; k += 256) cur[k] = tbase[k] + boff[k * NBLK + b];
  __syncthreads();
  int s = b * chunk, eend = min(e, s + chunk);
  for (int i = s + t; i < eend; i += 256) {
    int d = dst[i];
    int pos = atomicAdd(&cur[d >> 7], 1);
    ebuf[pos] = make_int2(src[i], d);
  }
}

// P4: per-bucket CSR finalize. LDS deg-count + scan + cursor scatter.
// Also writes deg/offs/dinv (replaces the global scans entirely).
__global__ __launch_bounds__(256) void k_p4(const int2* __restrict__ ebuf,
    const int* __restrict__ tbase, int* __restrict__ csr, int* __restrict__ offs,
    int* __restrict__ deg, float* __restrict__ dinv, int n, int nbuck, int etot) {
  __shared__ int dcnt[NPB];
  __shared__ int doff[NPB];
  __shared__ int dcur[NPB];
  int k = blockIdx.x, t = threadIdx.x;
  int s = tbase[k];
  int eend = (k + 1 < nbuck) ? tbase[k + 1] : etot;
  if (t < NPB) dcnt[t] = 0;
  __syncthreads();
  for (int i = s + t; i < eend; i += 256) atomicAdd(&dcnt[ebuf[i].y & (NPB - 1)], 1);
  __syncthreads();
  if (t < NPB) doff[t] = dcnt[t];
  __syncthreads();
  for (int d = 1; d < NPB; d <<= 1) {
    int add = 0;
    if (t < NPB && t >= d) add = doff[t - d];
    __syncthreads();
    if (t < NPB) doff[t] += add;
    __syncthreads();
  }
  if (t < NPB) {
    int ex = doff[t] - dcnt[t];  // exclusive
    dcur[t] = s + ex;
    int node = k * NPB + t;
    if (node < n) {
      offs[node] = s + ex;
      deg[node] = dcnt[t];
      dinv[node] = 1.0f / sqrtf((float)(dcnt[t] + 1));
    }
  }
  __syncthreads();
  for (int i = s + t; i < eend; i += 256) {
    int2 ed = ebuf[i];
    int pos = atomicAdd(&dcur[ed.y & (NPB - 1)], 1);
    csr[pos] = ed.x;
  }
}

// 4 nodes/block. lane = es*16+cg; 4-deep predicated slots -> 16 rows in flight.
__global__ __launch_bounds__(256) void k_agg(const ushort* __restrict__ xh,
    const int* __restrict__ csr, const int* __restrict__ offs,
    const int* __restrict__ degc, const float* __restrict__ dinv,
    ushort* __restrict__ yh, int n) {
  int node = blockIdx.x * 4 + (threadIdx.x >> 6);
  if (node >= n) return;
  int lane = threadIdx.x & 63;
  int es = lane >> 4;
  int cg = lane & 15;
  int o = offs[node], c = degc[node];
  float A[8] = {0.f, 0.f, 0.f, 0.f, 0.f, 0.f, 0.f, 0.f};
  for (int it = 0; it < c; it += 16) {
    float w[4];
    uint4 v[4];
#pragma unroll
    for (int u = 0; u < 4; ++u) {
      int ii = it + u * 4 + es;
      bool val = ii < c;
      int s = val ? csr[o + ii] : node;
      w[u] = val ? dinv[s] : 0.f;
      v[u] = *reinterpret_cast<const uint4*>(&xh[(size_t)s * IN_CH + cg * 8]);
    }
#pragma unroll
    for (int u = 0; u < 4; ++u) acc8(v[u], w[u], A);
  }
#pragma unroll
  for (int k = 0; k < 8; ++k) {
    A[k] += __shfl_xor(A[k], 16, 64);
    A[k] += __shfl_xor(A[k], 32, 64);
  }
  if (es == 0) {
    float dn = dinv[node];
    uint4 xs = *reinterpret_cast<const uint4*>(&xh[(size_t)node * IN_CH + cg * 8]);
    float xv[8] = {0.f, 0.f, 0.f, 0.f, 0.f, 0.f, 0.f, 0.f};
    acc8(xs, dn, xv);
    float v[8];
#pragma unroll
    for (int k = 0; k < 8; ++k) v[k] = (A[k] + xv[k]) * dn;
    uint4 w;
    w.x = pack2(v[0], v[1]);
    w.y = pack2(v[2], v[3]);
    w.z = pack2(v[4], v[5]);
    w.w = pack2(v[6], v[7]);
    *reinterpret_cast<uint4*>(&yh[(size_t)node * IN_CH + cg * 8]) = w;
  }
}

// MFMA GEMM(128->256 bf16)+bias+relu fused with per-graph pooling.
__global__ __launch_bounds__(256) void k_gemmpool(
    const ushort* __restrict__ yh, const ushort* __restrict__ w1t,
    const float* __restrict__ b1, const int* __restrict__ batch,
    float* __restrict__ pooled, int n) {
  __shared__ float part[4][HIDDEN];
  __shared__ int bl[GN];
  int t = threadIdx.x;
  int node0 = blockIdx.x * GN;

  if (t < GN) {
    int nd = node0 + t;
    bl[t] = (nd < n) ? batch[nd] : -1;
  }
  {
    float* pp = &part[0][0];
    for (int i = t; i < 4 * HIDDEN; i += 256) pp[i] = 0.f;
  }

  int wv = t >> 6, l = t & 63;
  int lr = l & 15;
  int lk = l >> 4;
  int colbase = wv * 64;

  f32x4 acc[4][4];
#pragma unroll
  for (int m = 0; m < 4; ++m)
#pragma unroll
    for (int nn = 0; nn < 4; ++nn) acc[m][nn] = (f32x4){0.f, 0.f, 0.f, 0.f};

#pragma unroll
  for (int kc = 0; kc < 4; ++kc) {
    short8 a[4], b[4];
#pragma unroll
    for (int m = 0; m < 4; ++m)
      a[m] = *reinterpret_cast<const short8*>(
          &yh[(size_t)(node0 + m * 16 + lr) * IN_CH + kc * 32 + lk * 8]);
#pragma unroll
    for (int nn = 0; nn < 4; ++nn)
      b[nn] = *reinterpret_cast<const short8*>(
          &w1t[(size_t)(colbase + nn * 16 + lr) * IN_CH + kc * 32 + lk * 8]);
#pragma unroll
    for (int m = 0; m < 4; ++m)
#pragma unroll
      for (int nn = 0; nn < 4; ++nn)
        acc[m][nn] = __builtin_amdgcn_mfma_f32_16x16x32_bf16(a[m], b[nn], acc[m][nn], 0, 0, 0);
  }

  __syncthreads();

  float bias[4];
#pragma unroll
  for (int nn = 0; nn < 4; ++nn) bias[nn] = b1[colbase + nn * 16 + lr];
  int g0 = bl[0];

#pragma unroll
  for (int m = 0; m < 4; ++m) {
    float s[4] = {0.f, 0.f, 0.f, 0.f};
    int gcur = -1;
#pragma unroll
    for (int j = 0; j < 4; ++j) {
      int row = m * 16 + lk * 4 + j;
      int node = node0 + row;
      int g = (node < n) ? bl[row] : -1;
      if (g != gcur) {
        if (gcur >= 0) {
          int gi = gcur - g0;
          if (gi < 4) {
#pragma unroll
            for (int nn = 0; nn < 4; ++nn)
              atomicAdd(&part[gi][colbase + nn * 16 + lr], s[nn]);
          } else {
#pragma unroll
            for (int nn = 0; nn < 4; ++nn)
              atomicAdd(&pooled[gcur * HIDDEN + colbase + nn * 16 + lr], s[nn]);
          }
        }
#pragma unroll
        for (int u = 0; u < 4; ++u) s[u] = 0.f;
        gcur = g;
      }
      if (g >= 0) {
#pragma unroll
        for (int nn = 0; nn < 4; ++nn)
          s[nn] += fmaxf(acc[m][nn][j] + bias[nn], 0.f);
      }
    }
    if (gcur >= 0) {
      int gi = gcur - g0;
      if (gi < 4) {
#pragma unroll
        for (int nn = 0; nn < 4; ++nn)
          atomicAdd(&part[gi][colbase + nn * 16 + lr], s[nn]);
      } else {
#pragma unroll
        for (int nn = 0; nn < 4; ++nn)
          atomicAdd(&pooled[gcur * HIDDEN + colbase + nn * 16 + lr], s[nn]);
      }
    }
  }

  __syncthreads();
  int lastIdx = min(GN, n - node0) - 1;
  int gmax = bl[lastIdx];
  int span = gmax - g0;
  if (span > 3) span = 3;
  for (int gi = 0; gi <= span; ++gi) {
    atomicAdd(&pooled[(g0 + gi) * HIDDEN + t], part[gi][t]);
  }
}

// One block per graph: cnt via binary search, mean, relu(p@w2+b2), @w3+b3.
__global__ __launch_bounds__(256) void k_head(const float* __restrict__ pooled,
    const int* __restrict__ batch, int n, const float* __restrict__ w2,
    const float* __restrict__ b2, const float* __restrict__ w3,
    const float* __restrict__ b3, float* __restrict__ out) {
  __shared__ float p[256];
  __shared__ float red[4];
  __shared__ int scnt;
  int g = blockIdx.x, t = threadIdx.x;
  if (t == 0) {
    int lo = 0, hi = n;
    while (lo < hi) { int mid = (lo + hi) >> 1; if (batch[mid] < g) lo = mid + 1; else hi = mid; }
    int a = lo;
    lo = 0; hi = n;
    int g1 = g + 1;
    while (lo < hi) { int mid = (lo + hi) >> 1; if (batch[mid] < g1) lo = mid + 1; else hi = mid; }
    scnt = lo - a;
  }
  __syncthreads();
  float c = (float)max(scnt, 1);
  p[t] = pooled[g * HIDDEN + t] / c;
  __syncthreads();
  float a = 0.f;
  for (int k = 0; k < 256; ++k) a += p[k] * w2[k * 256 + t];
  a += b2[t];
  a = fmaxf(a, 0.f);
  float part = a * w3[t];
  for (int off = 32; off > 0; off >>= 1) part += __shfl_down(part, off, 64);
  if ((t & 63) == 0) red[t >> 6] = part;
  __syncthreads();
  if (t == 0) out[g] = red[0] + red[1] + red[2] + red[3] + b3[0];
}

extern "C" void kernel_launch(void* const* d_in, const int* in_sizes, int n_in,
                              void* d_out, int out_size, void* d_ws, size_t ws_size,
                              hipStream_t stream) {
  const float* x    = (const float*)d_in[0];
  const int*   ei   = (const int*)d_in[1];
  const int*   batch= (const int*)d_in[2];
  const float* w1   = (const float*)d_in[3];
  const float* b1   = (const float*)d_in[4];
  const float* w2   = (const float*)d_in[5];
  const float* b2   = (const float*)d_in[6];
  const float* w3   = (const float*)d_in[7];
  const float* b3   = (const float*)d_in[8];
  float* out = (float*)d_out;

  int N = in_sizes[2];
  int E = in_sizes[1] / 2;
  const int* esrc = ei;
  const int* edst = ei + E;
  int nbuck = (N + NPB - 1) / NPB;
  int chunk = (E + NBLK - 1) / NBLK;

  // layout (ints): [ebuf E*2 (int2, 8B-aligned at base)][pooled 16384]
  // [offs N][deg N][dinv N][total 512][tbase 512][ghist 400*512]
  // [boff 512*400][csr E][w1t 16384 ints = 32768 ushorts][xh N*64][yh ...]
  int* W = (int*)d_ws;
  int2*   ebuf   = (int2*)W;
  int*    base1  = W + (size_t)E * 2;
  float*  pooled = (float*)base1;
  int*    offs   = base1 + N_GRAPHS * HIDDEN;
  int*    deg_i  = offs + N;
  float*  dinv   = (float*)(deg_i + N);
  int*    total  = (int*)(dinv + N);
  int*    tbase  = total + MAXBUCK;
  int*    ghist  = tbase + MAXBUCK;
  int*    boff   = ghist + NBLK * MAXBUCK;
  int*    csr    = boff + MAXBUCK * NBLK;
  ushort* w1t    = (ushort*)(csr + E);
  ushort* xh     = (ushort*)(csr + E + 16384);  // w1t is 16384 ints (32768 bf16)
  ushort* yh     = xh + (size_t)N * IN_CH;

  hipMemsetAsync(pooled, 0, (size_t)(N_GRAPHS * HIDDEN) * sizeof(float), stream);

  int total8 = N * 16;
  k_p1<<<NBLK, 256, 0, stream>>>(x, xh, w1, w1t, edst, ghist, total8, E, nbuck, chunk);
  k_p2a<<<nbuck, 512, 0, stream>>>(ghist, boff, total, nbuck);
  k_p2b<<<1, 512, 0, stream>>>(total, tbase, nbuck);
  k_p3<<<NBLK, 256, 0, stream>>>(esrc, edst, boff, tbase, ebuf, E, nbuck, chunk);
  k_p4<<<nbuck, 256, 0, stream>>>(ebuf, tbase, csr, offs, deg_i, dinv, N, nbuck, E);
  k_agg<<<(N + 3) / 4, 256, 0, stream>>>(xh, csr, offs, deg_i, dinv, yh, N);
  k_gemmpool<<<(N + GN - 1) / GN, 256, 0, stream>>>(yh, w1t, b1, batch, pooled, N);
  k_head<<<N_GRAPHS, 256, 0, stream>>>(pooled, batch, N, w2, b2, w3, b3, out);
}

// Round 14
// 126.499 us; speedup vs baseline: 1.2372x; 1.0344x over previous
//
#include <hip/hip_runtime.h>

#define IN_CH   128
#define HIDDEN  256
#define N_GRAPHS 64
#define GN 64      // nodes per gemm block
#define NPB 64     // nodes per bucket
#define LOGNPB 6
#define MAXBUCK 1024
#define NBLK 400   // edge-processing blocks

typedef short short8 __attribute__((ext_vector_type(8)));
typedef float f32x4 __attribute__((ext_vector_type(4)));

__device__ inline unsigned f2bf(float f) {
  unsigned u = __float_as_uint(f);
  return (u + 0x7fffu + ((u >> 16) & 1u)) >> 16;
}
__device__ inline unsigned pack2(float lo, float hi) {
  return (f2bf(hi) << 16) | f2bf(lo);
}
__device__ inline void acc8(uint4 v, float w, float* A) {
  A[0] += w * __uint_as_float(v.x << 16);
  A[1] += w * __uint_as_float(v.x & 0xffff0000u);
  A[2] += w * __uint_as_float(v.y << 16);
  A[3] += w * __uint_as_float(v.y & 0xffff0000u);
  A[4] += w * __uint_as_float(v.z << 16);
  A[5] += w * __uint_as_float(v.z & 0xffff0000u);
  A[6] += w * __uint_as_float(v.w << 16);
  A[7] += w * __uint_as_float(v.w & 0xffff0000u);
}

// P1: x->bf16 + w1->bf16^T casts (grid-stride) + pooled zero-init +
// per-block LDS bucket histogram.
__global__ __launch_bounds__(256) void k_p1(
    const float* __restrict__ x, ushort* __restrict__ xh,
    const float* __restrict__ w1, ushort* __restrict__ w1t,
    const int* __restrict__ dst, int* __restrict__ ghist,
    float* __restrict__ pooled, int total8, int e, int nbuck, int chunk) {
  __shared__ int h[MAXBUCK];
  int t = threadIdx.x, b = blockIdx.x;
  for (int k = t; k < nbuck; k += 256) h[k] = 0;
  int gid = b * 256 + t;
  const int nthr = NBLK * 256;
  for (int i = gid; i < total8; i += nthr) {
    const float4* xp = reinterpret_cast<const float4*>(x) + (size_t)i * 2;
    float4 a = xp[0], bb = xp[1];
    uint4 o;
    o.x = pack2(a.x, a.y);
    o.y = pack2(a.z, a.w);
    o.z = pack2(bb.x, bb.y);
    o.w = pack2(bb.z, bb.w);
    reinterpret_cast<uint4*>(xh)[i] = o;
  }
  if (gid < HIDDEN * IN_CH) {
    int nn = gid >> 7, k = gid & 127;
    w1t[gid] = (ushort)f2bf(w1[k * 256 + nn]);
  }
  if (gid < N_GRAPHS * HIDDEN) pooled[gid] = 0.f;
  __syncthreads();
  int s = b * chunk, eend = min(e, s + chunk);
  for (int i = s + t; i < eend; i += 256) atomicAdd(&h[dst[i] >> LOGNPB], 1);
  __syncthreads();
  for (int k = t; k < nbuck; k += 256) ghist[b * MAXBUCK + k] = h[k];
}

// P2a: per-bucket exclusive scan over the NBLK blocks; emit bucket totals.
__global__ __launch_bounds__(512) void k_p2a(const int* __restrict__ ghist,
    int* __restrict__ boff, int* __restrict__ total, int nbuck) {
  __shared__ int sm[512];
  int k = blockIdx.x, t = threadIdx.x;
  int v = (t < NBLK) ? ghist[t * MAXBUCK + k] : 0;
  sm[t] = v;
  __syncthreads();
  for (int d = 1; d < 512; d <<= 1) {
    int add = (t >= d) ? sm[t - d] : 0;
    __syncthreads();
    sm[t] += add;
    __syncthreads();
  }
  if (t < NBLK) boff[k * NBLK + t] = sm[t] - v;
  if (t == 511) total[k] = sm[511];
}

// P2b: exclusive scan of bucket totals -> tbase (nbuck <= 1024).
__global__ __launch_bounds__(1024) void k_p2b(const int* __restrict__ total,
    int* __restrict__ tbase, int nbuck) {
  __shared__ int sm[1024];
  int t = threadIdx.x;
  int v = (t < nbuck) ? total[t] : 0;
  sm[t] = v;
  __syncthreads();
  for (int d = 1; d < 1024; d <<= 1) {
    int add = (t >= d) ? sm[t - d] : 0;
    __syncthreads();
    sm[t] += add;
    __syncthreads();
  }
  if (t < nbuck) tbase[t] = sm[t] - v;
}

// P3: scatter edges into bucket-contiguous ebuf via LDS cursors.
__global__ __launch_bounds__(256) void k_p3(
    const int* __restrict__ src, const int* __restrict__ dst,
    const int* __restrict__ boff, const int* __restrict__ tbase,
    int2* __restrict__ ebuf, int e, int nbuck, int chunk) {
  __shared__ int cur[MAXBUCK];
  int t = threadIdx.x, b = blockIdx.x;
  for (int k = t; k < nbuck; k += 256) cur[k] = tbase[k] + boff[k * NBLK + b];
  __syncthreads();
  int s = b * chunk, eend = min(e, s + chunk);
  for (int i = s + t; i < eend; i += 256) {
    int d = dst[i];
    int pos = atomicAdd(&cur[d >> LOGNPB], 1);
    ebuf[pos] = make_int2(src[i], d);
  }
}

// P4: per-bucket CSR finalize. LDS deg-count + scan + cursor scatter.
// Writes offs (N+1 entries) + dinv; deg is implicit in offs.
__global__ __launch_bounds__(256) void k_p4(const int2* __restrict__ ebuf,
    const int* __restrict__ tbase, int* __restrict__ csr, int* __restrict__ offs,
    float* __restrict__ dinv, int n, int nbuck, int etot) {
  __shared__ int dcnt[NPB];
  __shared__ int doff[NPB];
  __shared__ int dcur[NPB];
  int k = blockIdx.x, t = threadIdx.x;
  int s = tbase[k];
  int eend = (k + 1 < nbuck) ? tbase[k + 1] : etot;
  if (t < NPB) dcnt[t] = 0;
  __syncthreads();
  for (int i = s + t; i < eend; i += 256) atomicAdd(&dcnt[ebuf[i].y & (NPB - 1)], 1);
  __syncthreads();
  if (t < NPB) doff[t] = dcnt[t];
  __syncthreads();
  for (int d = 1; d < NPB; d <<= 1) {
    int add = 0;
    if (t < NPB && t >= d) add = doff[t - d];
    __syncthreads();
    if (t < NPB) doff[t] += add;
    __syncthreads();
  }
  if (t < NPB) {
    int ex = doff[t] - dcnt[t];  // exclusive
    dcur[t] = s + ex;
    int node = k * NPB + t;
    if (node < n) {
      offs[node] = s + ex;
      dinv[node] = 1.0f / sqrtf((float)(dcnt[t] + 1));
    }
  }
  if (k == nbuck - 1 && t == 0) offs[n] = etot;
  __syncthreads();
  for (int i = s + t; i < eend; i += 256) {
    int2 ed = ebuf[i];
    int pos = atomicAdd(&dcur[ed.y & (NPB - 1)], 1);
    csr[pos] = ed.x;
  }
}

// 4 nodes/block. lane = es*16+cg; 4-deep predicated slots -> 16 rows in flight.
__global__ __launch_bounds__(256) void k_agg(const ushort* __restrict__ xh,
    const int* __restrict__ csr, const int* __restrict__ offs,
    const float* __restrict__ dinv, ushort* __restrict__ yh, int n) {
  int node = blockIdx.x * 4 + (threadIdx.x >> 6);
  if (node >= n) return;
  int lane = threadIdx.x & 63;
  int es = lane >> 4;
  int cg = lane & 15;
  int o = offs[node];
  int c = offs[node + 1] - o;
  float A[8] = {0.f, 0.f, 0.f, 0.f, 0.f, 0.f, 0.f, 0.f};
  for (int it = 0; it < c; it += 16) {
    float w[4];
    uint4 v[4];
#pragma unroll
    for (int u = 0; u < 4; ++u) {
      int ii = it + u * 4 + es;
      bool val = ii < c;
      int s = val ? csr[o + ii] : node;
      w[u] = val ? dinv[s] : 0.f;
      v[u] = *reinterpret_cast<const uint4*>(&xh[(size_t)s * IN_CH + cg * 8]);
    }
#pragma unroll
    for (int u = 0; u < 4; ++u) acc8(v[u], w[u], A);
  }
#pragma unroll
  for (int k = 0; k < 8; ++k) {
    A[k] += __shfl_xor(A[k], 16, 64);
    A[k] += __shfl_xor(A[k], 32, 64);
  }
  if (es == 0) {
    float dn = dinv[node];
    uint4 xs = *reinterpret_cast<const uint4*>(&xh[(size_t)node * IN_CH + cg * 8]);
    float xv[8] = {0.f, 0.f, 0.f, 0.f, 0.f, 0.f, 0.f, 0.f};
    acc8(xs, dn, xv);
    float v[8];
#pragma unroll
    for (int k = 0; k < 8; ++k) v[k] = (A[k] + xv[k]) * dn;
    uint4 w;
    w.x = pack2(v[0], v[1]);
    w.y = pack2(v[2], v[3]);
    w.z = pack2(v[4], v[5]);
    w.w = pack2(v[6], v[7]);
    *reinterpret_cast<uint4*>(&yh[(size_t)node * IN_CH + cg * 8]) = w;
  }
}

// MFMA GEMM(128->256 bf16)+bias+relu fused with per-graph pooling.
__global__ __launch_bounds__(256) void k_gemmpool(
    const ushort* __restrict__ yh, const ushort* __restrict__ w1t,
    const float* __restrict__ b1, const int* __restrict__ batch,
    float* __restrict__ pooled, int n) {
  __shared__ float part[4][HIDDEN];
  __shared__ int bl[GN];
  int t = threadIdx.x;
  int node0 = blockIdx.x * GN;

  if (t < GN) {
    int nd = node0 + t;
    bl[t] = (nd < n) ? batch[nd] : -1;
  }
  {
    float* pp = &part[0][0];
    for (int i = t; i < 4 * HIDDEN; i += 256) pp[i] = 0.f;
  }

  int wv = t >> 6, l = t & 63;
  int lr = l & 15;
  int lk = l >> 4;
  int colbase = wv * 64;

  f32x4 acc[4][4];
#pragma unroll
  for (int m = 0; m < 4; ++m)
#pragma unroll
    for (int nn = 0; nn < 4; ++nn) acc[m][nn] = (f32x4){0.f, 0.f, 0.f, 0.f};

#pragma unroll
  for (int kc = 0; kc < 4; ++kc) {
    short8 a[4], b[4];
#pragma unroll
    for (int m = 0; m < 4; ++m)
      a[m] = *reinterpret_cast<const short8*>(
          &yh[(size_t)(node0 + m * 16 + lr) * IN_CH + kc * 32 + lk * 8]);
#pragma unroll
    for (int nn = 0; nn < 4; ++nn)
      b[nn] = *reinterpret_cast<const short8*>(
          &w1t[(size_t)(colbase + nn * 16 + lr) * IN_CH + kc * 32 + lk * 8]);
#pragma unroll
    for (int m = 0; m < 4; ++m)
#pragma unroll
      for (int nn = 0; nn < 4; ++nn)
        acc[m][nn] = __builtin_amdgcn_mfma_f32_16x16x32_bf16(a[m], b[nn], acc[m][nn], 0, 0, 0);
  }

  __syncthreads();

  float bias[4];
#pragma unroll
  for (int nn = 0; nn < 4; ++nn) bias[nn] = b1[colbase + nn * 16 + lr];
  int g0 = bl[0];

#pragma unroll
  for (int m = 0; m < 4; ++m) {
    float s[4] = {0.f, 0.f, 0.f, 0.f};
    int gcur = -1;
#pragma unroll
    for (int j = 0; j < 4; ++j) {
      int row = m * 16 + lk * 4 + j;
      int node = node0 + row;
      int g = (node < n) ? bl[row] : -1;
      if (g != gcur) {
        if (gcur >= 0) {
          int gi = gcur - g0;
          if (gi < 4) {
#pragma unroll
            for (int nn = 0; nn < 4; ++nn)
              atomicAdd(&part[gi][colbase + nn * 16 + lr], s[nn]);
          } else {
#pragma unroll
            for (int nn = 0; nn < 4; ++nn)
              atomicAdd(&pooled[gcur * HIDDEN + colbase + nn * 16 + lr], s[nn]);
          }
        }
#pragma unroll
        for (int u = 0; u < 4; ++u) s[u] = 0.f;
        gcur = g;
      }
      if (g >= 0) {
#pragma unroll
        for (int nn = 0; nn < 4; ++nn)
          s[nn] += fmaxf(acc[m][nn][j] + bias[nn], 0.f);
      }
    }
    if (gcur >= 0) {
      int gi = gcur - g0;
      if (gi < 4) {
#pragma unroll
        for (int nn = 0; nn < 4; ++nn)
          atomicAdd(&part[gi][colbase + nn * 16 + lr], s[nn]);
      } else {
#pragma unroll
        for (int nn = 0; nn < 4; ++nn)
          atomicAdd(&pooled[gcur * HIDDEN + colbase + nn * 16 + lr], s[nn]);
      }
    }
  }

  __syncthreads();
  int lastIdx = min(GN, n - node0) - 1;
  int gmax = bl[lastIdx];
  int span = gmax - g0;
  if (span > 3) span = 3;
  for (int gi = 0; gi <= span; ++gi) {
    atomicAdd(&pooled[(g0 + gi) * HIDDEN + t], part[gi][t]);
  }
}

// One block per graph: cnt via binary search, mean, relu(p@w2+b2), @w3+b3.
__global__ __launch_bounds__(256) void k_head(const float* __restrict__ pooled,
    const int* __restrict__ batch, int n, const float* __restrict__ w2,
    const float* __restrict__ b2, const float* __restrict__ w3,
    const float* __restrict__ b3, float* __restrict__ out) {
  __shared__ float p[256];
  __shared__ float red[4];
  __shared__ int scnt;
  int g = blockIdx.x, t = threadIdx.x;
  if (t == 0) {
    int lo = 0, hi = n;
    while (lo < hi) { int mid = (lo + hi) >> 1; if (batch[mid] < g) lo = mid + 1; else hi = mid; }
    int a = lo;
    lo = 0; hi = n;
    int g1 = g + 1;
    while (lo < hi) { int mid = (lo + hi) >> 1; if (batch[mid] < g1) lo = mid + 1; else hi = mid; }
    scnt = lo - a;
  }
  __syncthreads();
  float c = (float)max(scnt, 1);
  p[t] = pooled[g * HIDDEN + t] / c;
  __syncthreads();
  float a = 0.f;
  for (int k = 0; k < 256; ++k) a += p[k] * w2[k * 256 + t];
  a += b2[t];
  a = fmaxf(a, 0.f);
  float part = a * w3[t];
  for (int off = 32; off > 0; off >>= 1) part += __shfl_down(part, off, 64);
  if ((t & 63) == 0) red[t >> 6] = part;
  __syncthreads();
  if (t == 0) out[g] = red[0] + red[1] + red[2] + red[3] + b3[0];
}

extern "C" void kernel_launch(void* const* d_in, const int* in_sizes, int n_in,
                              void* d_out, int out_size, void* d_ws, size_t ws_size,
                              hipStream_t stream) {
  const float* x    = (const float*)d_in[0];
  const int*   ei   = (const int*)d_in[1];
  const int*   batch= (const int*)d_in[2];
  const float* w1   = (const float*)d_in[3];
  const float* b1   = (const float*)d_in[4];
  const float* w2   = (const float*)d_in[5];
  const float* b2   = (const float*)d_in[6];
  const float* w3   = (const float*)d_in[7];
  const float* b3   = (const float*)d_in[8];
  float* out = (float*)d_out;

  int N = in_sizes[2];
  int E = in_sizes[1] / 2;
  const int* esrc = ei;
  const int* edst = ei + E;
  int nbuck = (N + NPB - 1) / NPB;
  int chunk = (E + NBLK - 1) / NBLK;

  // layout (ints): [ebuf E*2 (int2)][pooled 16384][offs N+1][dinv N]
  // [total 1024][tbase 1024][ghist 400*1024][boff 1024*400][csr E]
  // [w1t 16384 ints][xh N*64][yh N*64]
  int* W = (int*)d_ws;
  int2*   ebuf   = (int2*)W;
  int*    base1  = W + (size_t)E * 2;
  float*  pooled = (float*)base1;
  int*    offs   = base1 + N_GRAPHS * HIDDEN;
  float*  dinv   = (float*)(offs + N + 1);
  int*    total  = (int*)(dinv + N);
  int*    tbase  = total + MAXBUCK;
  int*    ghist  = tbase + MAXBUCK;
  int*    boff   = ghist + NBLK * MAXBUCK;
  int*    csr    = boff + MAXBUCK * NBLK;
  ushort* w1t    = (ushort*)(csr + E);
  ushort* xh     = (ushort*)(csr + E + 16384);  // w1t = 16384 ints (32768 bf16)
  ushort* yh     = xh + (size_t)N * IN_CH;

  int total8 = N * 16;
  k_p1<<<NBLK, 256, 0, stream>>>(x, xh, w1, w1t, edst, ghist, pooled,
                                 total8, E, nbuck, chunk);
  k_p2a<<<nbuck, 512, 0, stream>>>(ghist, boff, total, nbuck);
  k_p2b<<<1, 1024, 0, stream>>>(total, tbase, nbuck);
  k_p3<<<NBLK, 256, 0, stream>>>(esrc, edst, boff, tbase, ebuf, E, nbuck, chunk);
  k_p4<<<nbuck, 256, 0, stream>>>(ebuf, tbase, csr, offs, dinv, N, nbuck, E);
  k_agg<<<(N + 3) / 4, 256, 0, stream>>>(xh, csr, offs, dinv, yh, N);
  k_gemmpool<<<(N + GN - 1) / GN, 256, 0, stream>>>(yh, w1t, b1, batch, pooled, N);
  k_head<<<N_GRAPHS, 256, 0, stream>>>(pooled, batch, N, w2, b2, w3, b3, out);
}

// Round 15
// 123.948 us; speedup vs baseline: 1.2627x; 1.0206x over previous
//
#include <hip/hip_runtime.h>

#define IN_CH   128
#define HIDDEN  256
#define N_GRAPHS 64
#define GN 64      // nodes per gemm block
#define NPB 64     // nodes per bucket
#define LOGNPB 6
#define MAXBUCK 1024
#define NBLK 400   // edge-processing blocks

typedef short short8 __attribute__((ext_vector_type(8)));
typedef float f32x4 __attribute__((ext_vector_type(4)));

__device__ inline unsigned f2bf(float f) {
  unsigned u = __float_as_uint(f);
  return (u + 0x7fffu + ((u >> 16) & 1u)) >> 16;
}
__device__ inline unsigned pack2(float lo, float hi) {
  return (f2bf(hi) << 16) | f2bf(lo);
}
__device__ inline void acc8(uint4 v, float w, float* A) {
  A[0] += w * __uint_as_float(v.x << 16);
  A[1] += w * __uint_as_float(v.x & 0xffff0000u);
  A[2] += w * __uint_as_float(v.y << 16);
  A[3] += w * __uint_as_float(v.y & 0xffff0000u);
  A[4] += w * __uint_as_float(v.z << 16);
  A[5] += w * __uint_as_float(v.z & 0xffff0000u);
  A[6] += w * __uint_as_float(v.w << 16);
  A[7] += w * __uint_as_float(v.w & 0xffff0000u);
}

// P1: x->bf16 + w1->bf16^T casts (grid-stride) + pooled zero-init +
// per-block LDS bucket histogram.
__global__ __launch_bounds__(256) void k_p1(
    const float* __restrict__ x, ushort* __restrict__ xh,
    const float* __restrict__ w1, ushort* __restrict__ w1t,
    const int* __restrict__ dst, int* __restrict__ ghist,
    float* __restrict__ pooled, int total8, int e, int nbuck, int chunk) {
  __shared__ int h[MAXBUCK];
  int t = threadIdx.x, b = blockIdx.x;
  for (int k = t; k < nbuck; k += 256) h[k] = 0;
  int gid = b * 256 + t;
  const int nthr = NBLK * 256;
  for (int i = gid; i < total8; i += nthr) {
    const float4* xp = reinterpret_cast<const float4*>(x) + (size_t)i * 2;
    float4 a = xp[0], bb = xp[1];
    uint4 o;
    o.x = pack2(a.x, a.y);
    o.y = pack2(a.z, a.w);
    o.z = pack2(bb.x, bb.y);
    o.w = pack2(bb.z, bb.w);
    reinterpret_cast<uint4*>(xh)[i] = o;
  }
  if (gid < HIDDEN * IN_CH) {
    int nn = gid >> 7, k = gid & 127;
    w1t[gid] = (ushort)f2bf(w1[k * 256 + nn]);
  }
  if (gid < N_GRAPHS * HIDDEN) pooled[gid] = 0.f;
  __syncthreads();
  int s = b * chunk, eend = min(e, s + chunk);
  for (int i = s + t; i < eend; i += 256) atomicAdd(&h[dst[i] >> LOGNPB], 1);
  __syncthreads();
  for (int k = t; k < nbuck; k += 256) ghist[b * MAXBUCK + k] = h[k];
}

// P2a: per-bucket exclusive scan over the NBLK blocks; emit bucket totals.
__global__ __launch_bounds__(512) void k_p2a(const int* __restrict__ ghist,
    int* __restrict__ boff, int* __restrict__ total, int nbuck) {
  __shared__ int sm[512];
  int k = blockIdx.x, t = threadIdx.x;
  int v = (t < NBLK) ? ghist[t * MAXBUCK + k] : 0;
  sm[t] = v;
  __syncthreads();
  for (int d = 1; d < 512; d <<= 1) {
    int add = (t >= d) ? sm[t - d] : 0;
    __syncthreads();
    sm[t] += add;
    __syncthreads();
  }
  if (t < NBLK) boff[k * NBLK + t] = sm[t] - v;
  if (t == 511) total[k] = sm[511];
}

// P3: scatter edges into bucket-contiguous ebuf via LDS cursors.
// Computes the bucket-total exclusive scan (tbase) in-block (replaces p2b).
// ebuf entry: src (low 16b, N<65536) | dst-within-bucket (bits 16..21).
__global__ __launch_bounds__(256) void k_p3(
    const int* __restrict__ src, const int* __restrict__ dst,
    const int* __restrict__ boff, const int* __restrict__ total,
    int* __restrict__ ebuf, int e, int nbuck, int chunk) {
  __shared__ int cur[MAXBUCK];
  __shared__ int ts[256];
  int t = threadIdx.x, b = blockIdx.x;
  // exclusive scan of total[] into cur[], 4 entries/thread
  int t4 = t * 4;
  int v0 = (t4 + 0 < nbuck) ? total[t4 + 0] : 0;
  int v1 = (t4 + 1 < nbuck) ? total[t4 + 1] : 0;
  int v2 = (t4 + 2 < nbuck) ? total[t4 + 2] : 0;
  int v3 = (t4 + 3 < nbuck) ? total[t4 + 3] : 0;
  int lsum = v0 + v1 + v2 + v3;
  ts[t] = lsum;
  __syncthreads();
  for (int d = 1; d < 256; d <<= 1) {
    int add = (t >= d) ? ts[t - d] : 0;
    __syncthreads();
    ts[t] += add;
    __syncthreads();
  }
  int base = ts[t] - lsum;
  cur[t4 + 0] = base;
  cur[t4 + 1] = base + v0;
  cur[t4 + 2] = base + v0 + v1;
  cur[t4 + 3] = base + v0 + v1 + v2;
  __syncthreads();
  for (int k = t; k < nbuck; k += 256) cur[k] += boff[k * NBLK + b];
  __syncthreads();
  int s = b * chunk, eend = min(e, s + chunk);
  for (int i = s + t; i < eend; i += 256) {
    int d = dst[i];
    int pos = atomicAdd(&cur[d >> LOGNPB], 1);
    ebuf[pos] = (src[i] & 0xffff) | ((d & (NPB - 1)) << 16);
  }
}

// P4: per-bucket CSR finalize. Computes own tbase via strided sum (no p2b).
// LDS deg-count + scan + cursor scatter; writes offs (N+1) + dinv; csr = ushort.
__global__ __launch_bounds__(256) void k_p4(const int* __restrict__ ebuf,
    const int* __restrict__ total, ushort* __restrict__ csr, int* __restrict__ offs,
    float* __restrict__ dinv, int n, int nbuck, int etot) {
  __shared__ int dcnt[NPB];
  __shared__ int doff[NPB];
  __shared__ int dcur[NPB];
  __shared__ int red[256];
  int k = blockIdx.x, t = threadIdx.x;
  int partial = 0;
  for (int i = t; i < k; i += 256) partial += total[i];
  red[t] = partial;
  if (t < NPB) dcnt[t] = 0;
  __syncthreads();
  for (int d = 128; d > 0; d >>= 1) {
    if (t < d) red[t] += red[t + d];
    __syncthreads();
  }
  int s = red[0];
  int eend = s + total[k];
  for (int i = s + t; i < eend; i += 256)
    atomicAdd(&dcnt[(ebuf[i] >> 16) & (NPB - 1)], 1);
  __syncthreads();
  if (t < NPB) doff[t] = dcnt[t];
  __syncthreads();
  for (int d = 1; d < NPB; d <<= 1) {
    int add = 0;
    if (t < NPB && t >= d) add = doff[t - d];
    __syncthreads();
    if (t < NPB) doff[t] += add;
    __syncthreads();
  }
  if (t < NPB) {
    int ex = doff[t] - dcnt[t];  // exclusive
    dcur[t] = s + ex;
    int node = k * NPB + t;
    if (node < n) {
      offs[node] = s + ex;
      dinv[node] = 1.0f / sqrtf((float)(dcnt[t] + 1));
    }
  }
  if (k == nbuck - 1 && t == 0) offs[n] = etot;
  __syncthreads();
  for (int i = s + t; i < eend; i += 256) {
    int v = ebuf[i];
    int pos = atomicAdd(&dcur[(v >> 16) & (NPB - 1)], 1);
    csr[pos] = (ushort)v;
  }
}

// 4 nodes/block. lane = es*16+cg; 4-deep predicated slots -> 16 rows in flight.
// Junk (out-of-degree) slots load row 0 with w=0: one L1-resident line, ~free.
__global__ __launch_bounds__(256) void k_agg(const ushort* __restrict__ xh,
    const ushort* __restrict__ csr, const int* __restrict__ offs,
    const float* __restrict__ dinv, ushort* __restrict__ yh, int n) {
  int node = blockIdx.x * 4 + (threadIdx.x >> 6);
  if (node >= n) return;
  int lane = threadIdx.x & 63;
  int es = lane >> 4;
  int cg = lane & 15;
  int o = offs[node];
  int c = offs[node + 1] - o;
  float A[8] = {0.f, 0.f, 0.f, 0.f, 0.f, 0.f, 0.f, 0.f};
  for (int it = 0; it < c; it += 16) {
    float w[4];
    uint4 v[4];
#pragma unroll
    for (int u = 0; u < 4; ++u) {
      int ii = it + u * 4 + es;
      bool val = ii < c;
      int s = val ? (int)csr[o + ii] : 0;   // junk -> row 0 (L1 broadcast)
      w[u] = val ? dinv[s] : 0.f;
      v[u] = *reinterpret_cast<const uint4*>(&xh[(size_t)s * IN_CH + cg * 8]);
    }
#pragma unroll
    for (int u = 0; u < 4; ++u) acc8(v[u], w[u], A);
  }
#pragma unroll
  for (int k = 0; k < 8; ++k) {
    A[k] += __shfl_xor(A[k], 16, 64);
    A[k] += __shfl_xor(A[k], 32, 64);
  }
  if (es == 0) {
    float dn = dinv[node];
    uint4 xs = *reinterpret_cast<const uint4*>(&xh[(size_t)node * IN_CH + cg * 8]);
    float xv[8] = {0.f, 0.f, 0.f, 0.f, 0.f, 0.f, 0.f, 0.f};
    acc8(xs, dn, xv);
    float v[8];
#pragma unroll
    for (int k = 0; k < 8; ++k) v[k] = (A[k] + xv[k]) * dn;
    uint4 w;
    w.x = pack2(v[0], v[1]);
    w.y = pack2(v[2], v[3]);
    w.z = pack2(v[4], v[5]);
    w.w = pack2(v[6], v[7]);
    *reinterpret_cast<uint4*>(&yh[(size_t)node * IN_CH + cg * 8]) = w;
  }
}

// MFMA GEMM(128->256 bf16)+bias+relu fused with per-graph pooling.
__global__ __launch_bounds__(256) void k_gemmpool(
    const ushort* __restrict__ yh, const ushort* __restrict__ w1t,
    const float* __restrict__ b1, const int* __restrict__ batch,
    float* __restrict__ pooled, int n) {
  __shared__ float part[4][HIDDEN];
  __shared__ int bl[GN];
  int t = threadIdx.x;
  int node0 = blockIdx.x * GN;

  if (t < GN) {
    int nd = node0 + t;
    bl[t] = (nd < n) ? batch[nd] : -1;
  }
  {
    float* pp = &part[0][0];
    for (int i = t; i < 4 * HIDDEN; i += 256) pp[i] = 0.f;
  }

  int wv = t >> 6, l = t & 63;
  int lr = l & 15;
  int lk = l >> 4;
  int colbase = wv * 64;

  f32x4 acc[4][4];
#pragma unroll
  for (int m = 0; m < 4; ++m)
#pragma unroll
    for (int nn = 0; nn < 4; ++nn) acc[m][nn] = (f32x4){0.f, 0.f, 0.f, 0.f};

#pragma unroll
  for (int kc = 0; kc < 4; ++kc) {
    short8 a[4], b[4];
#pragma unroll
    for (int m = 0; m < 4; ++m)
      a[m] = *reinterpret_cast<const short8*>(
          &yh[(size_t)(node0 + m * 16 + lr) * IN_CH + kc * 32 + lk * 8]);
#pragma unroll
    for (int nn = 0; nn < 4; ++nn)
      b[nn] = *reinterpret_cast<const short8*>(
          &w1t[(size_t)(colbase + nn * 16 + lr) * IN_CH + kc * 32 + lk * 8]);
#pragma unroll
    for (int m = 0; m < 4; ++m)
#pragma unroll
      for (int nn = 0; nn < 4; ++nn)
        acc[m][nn] = __builtin_amdgcn_mfma_f32_16x16x32_bf16(a[m], b[nn], acc[m][nn], 0, 0, 0);
  }

  __syncthreads();

  float bias[4];
#pragma unroll
  for (int nn = 0; nn < 4; ++nn) bias[nn] = b1[colbase + nn * 16 + lr];
  int g0 = bl[0];

#pragma unroll
  for (int m = 0; m < 4; ++m) {
    float s[4] = {0.f, 0.f, 0.f, 0.f};
    int gcur = -1;
#pragma unroll
    for (int j = 0; j < 4; ++j) {
      int row = m * 16 + lk * 4 + j;
      int node = node0 + row;
      int g = (node < n) ? bl[row] : -1;
      if (g != gcur) {
        if (gcur >= 0) {
          int gi = gcur - g0;
          if (gi < 4) {
#pragma unroll
            for (int nn = 0; nn < 4; ++nn)
              atomicAdd(&part[gi][colbase + nn * 16 + lr], s[nn]);
          } else {
#pragma unroll
            for (int nn = 0; nn < 4; ++nn)
              atomicAdd(&pooled[gcur * HIDDEN + colbase + nn * 16 + lr], s[nn]);
          }
        }
#pragma unroll
        for (int u = 0; u < 4; ++u) s[u] = 0.f;
        gcur = g;
      }
      if (g >= 0) {
#pragma unroll
        for (int nn = 0; nn < 4; ++nn)
          s[nn] += fmaxf(acc[m][nn][j] + bias[nn], 0.f);
      }
    }
    if (gcur >= 0) {
      int gi = gcur - g0;
      if (gi < 4) {
#pragma unroll
        for (int nn = 0; nn < 4; ++nn)
          atomicAdd(&part[gi][colbase + nn * 16 + lr], s[nn]);
      } else {
#pragma unroll
        for (int nn = 0; nn < 4; ++nn)
          atomicAdd(&pooled[gcur * HIDDEN + colbase + nn * 16 + lr], s[nn]);
      }
    }
  }

  __syncthreads();
  int lastIdx = min(GN, n - node0) - 1;
  int gmax = bl[lastIdx];
  int span = gmax - g0;
  if (span > 3) span = 3;
  for (int gi = 0; gi <= span; ++gi) {
    atomicAdd(&pooled[(g0 + gi) * HIDDEN + t], part[gi][t]);
  }
}

// One block per graph: cnt via binary search, mean, relu(p@w2+b2), @w3+b3.
__global__ __launch_bounds__(256) void k_head(const float* __restrict__ pooled,
    const int* __restrict__ batch, int n, const float* __restrict__ w2,
    const float* __restrict__ b2, const float* __restrict__ w3,
    const float* __restrict__ b3, float* __restrict__ out) {
  __shared__ float p[256];
  __shared__ float red[4];
  __shared__ int scnt;
  int g = blockIdx.x, t = threadIdx.x;
  if (t == 0) {
    int lo = 0, hi = n;
    while (lo < hi) { int mid = (lo + hi) >> 1; if (batch[mid] < g) lo = mid + 1; else hi = mid; }
    int a = lo;
    lo = 0; hi = n;
    int g1 = g + 1;
    while (lo < hi) { int mid = (lo + hi) >> 1; if (batch[mid] < g1) lo = mid + 1; else hi = mid; }
    scnt = lo - a;
  }
  __syncthreads();
  float c = (float)max(scnt, 1);
  p[t] = pooled[g * HIDDEN + t] / c;
  __syncthreads();
  float a = 0.f;
  for (int k = 0; k < 256; ++k) a += p[k] * w2[k * 256 + t];
  a += b2[t];
  a = fmaxf(a, 0.f);
  float part = a * w3[t];
  for (int off = 32; off > 0; off >>= 1) part += __shfl_down(part, off, 64);
  if ((t & 63) == 0) red[t >> 6] = part;
  __syncthreads();
  if (t == 0) out[g] = red[0] + red[1] + red[2] + red[3] + b3[0];
}

extern "C" void kernel_launch(void* const* d_in, const int* in_sizes, int n_in,
                              void* d_out, int out_size, void* d_ws, size_t ws_size,
                              hipStream_t stream) {
  const float* x    = (const float*)d_in[0];
  const int*   ei   = (const int*)d_in[1];
  const int*   batch= (const int*)d_in[2];
  const float* w1   = (const float*)d_in[3];
  const float* b1   = (const float*)d_in[4];
  const float* w2   = (const float*)d_in[5];
  const float* b2   = (const float*)d_in[6];
  const float* w3   = (const float*)d_in[7];
  const float* b3   = (const float*)d_in[8];
  float* out = (float*)d_out;

  int N = in_sizes[2];
  int E = in_sizes[1] / 2;
  const int* esrc = ei;
  const int* edst = ei + E;
  int nbuck = (N + NPB - 1) / NPB;
  int chunk = (E + NBLK - 1) / NBLK;

  // layout (ints): [ebuf E][pooled 16384][offs N+1][dinv N][total 1024]
  // [ghist 400*1024][boff 1024*400][csr E ushorts = (E+1)/2 ints]
  // [w1t 16384 ints][xh N*64][yh N*64]
  int* W = (int*)d_ws;
  int*    ebuf   = W;
  int*    base1  = W + (size_t)E;
  float*  pooled = (float*)base1;
  int*    offs   = base1 + N_GRAPHS * HIDDEN;
  float*  dinv   = (float*)(offs + N + 1);
  int*    total  = (int*)(dinv + N);
  int*    ghist  = total + MAXBUCK;
  int*    boff   = ghist + NBLK * MAXBUCK;
  ushort* csr    = (ushort*)(boff + MAXBUCK * NBLK);
  int*    after_csr = boff + MAXBUCK * NBLK + (E + 1) / 2;
  ushort* w1t    = (ushort*)after_csr;
  ushort* xh     = (ushort*)(after_csr + 16384);  // w1t = 16384 ints (32768 bf16)
  ushort* yh     = xh + (size_t)N * IN_CH;

  int total8 = N * 16;
  k_p1<<<NBLK, 256, 0, stream>>>(x, xh, w1, w1t, edst, ghist, pooled,
                                 total8, E, nbuck, chunk);
  k_p2a<<<nbuck, 512, 0, stream>>>(ghist, boff, total, nbuck);
  k_p3<<<NBLK, 256, 0, stream>>>(esrc, edst, boff, total, ebuf, E, nbuck, chunk);
  k_p4<<<nbuck, 256, 0, stream>>>(ebuf, total, csr, offs, dinv, N, nbuck, E);
  k_agg<<<(N + 3) / 4, 256, 0, stream>>>(xh, csr, offs, dinv, yh, N);
  k_gemmpool<<<(N + GN - 1) / GN, 256, 0, stream>>>(yh, w1t, b1, batch, pooled, N);
  k_head<<<N_GRAPHS, 256, 0, stream>>>(pooled, batch, N, w2, b2, w3, b3, out);
}